// Round 14
// baseline (277.514 us; speedup 1.0000x reference)
//
#include <hip/hip_runtime.h>
#include <hip/hip_bf16.h>
#include <hip/hip_fp16.h>

#define N_NODES 50000
#define N_EDGES 1600000
#define NPB    50      // nodes per bucket
#define NBUK   1000    // NPB*NBUK == N_NODES
#define NSL    8       // XCD slices
#define BCAPS  320     // slots per (bucket,slice): mean 200, +8.5 sigma
#define BCAPH  1280    // 4*BCAPS, per bucket-half
#define GEMMB  782     // GEMM blocks (in k2)
#define PARTB  512     // partition blocks (in k1, first)
#define ELERB  391     // el/er blocks (in k1)
#define BUKB   2000    // bucket blocks (in k2, first)
#define CHUNK  3125    // edges per partition block (512*3125 = 1.6M)
#define BD     8       // LDS bin depth (lambda=3.1, overflow ~0.5% -> fallback)

typedef __attribute__((ext_vector_type(8))) short short8;
typedef __attribute__((ext_vector_type(4))) float f32x4;

__device__ __forceinline__ unsigned short f2bf(float f) {
  union { float f; unsigned int i; } v; v.f = f;
  unsigned int i = v.i;
  unsigned int r = i + 0x7FFFu + ((i >> 16) & 1u);
  return (unsigned short)(r >> 16);
}

// ---------------- Kernel 1: partition  ||  el/er from h (fp32) --------------
// Blocks [0,512): LDS-binned edge partition (verbatim round-7 win).
// Blocks [512,903): el/er = h @ (W@Wl^T), h @ (W@Wr^T). Folding the
// projection (el=(h@W)@Wl^T == h@(W@Wl^T)) makes el/er independent of the
// MFMA GEMM -> k_bucket no longer waits on the GEMM (false dependency cut).
// fp32 throughout: MORE accurate than the old bf16-accumulator-derived el/er.
// Wfold lives in per-lane REGISTERS (lane l owns rows 4l..4l+3): no LDS.
__global__ __launch_bounds__(256) void k_peler(const float* __restrict__ hmat,
    const float* __restrict__ Wmat,
    const float* __restrict__ Wl, const float* __restrict__ Wr,
    const int* __restrict__ ei, int* __restrict__ bcnt,
    unsigned int* __restrict__ raw,
    float* __restrict__ el, float* __restrict__ er) {
  __shared__ __align__(16) char smem[36864];
  const int t = threadIdx.x;
  if (blockIdx.x < PARTB) {
    // ---- LDS-binned partition path (verbatim) ----
    int* scnt = (int*)smem;                            // [1000] counters (4KB)
    unsigned int* sbin = (unsigned int*)(smem + 4000); // [1000][BD] bins (32KB)
    const int pj = blockIdx.x;
    const int slice = blockIdx.x & 7;                  // XCD-local cell
    for (int i = t; i < NBUK; i += 256) scnt[i] = 0;
    __syncthreads();
    const int e0 = pj * CHUNK;
    for (int e = e0 + t; e < e0 + CHUNK; e += 256) {
      int s = ei[e], d = ei[N_EDGES + e];
      int b = s / NPB;
      int sl = s - b * NPB;
      unsigned int val = ((unsigned int)d << 8) | (unsigned int)sl;
      int p = atomicAdd(&scnt[b], 1);                  // LDS atomic (cheap)
      if (p < BD) {
        sbin[b * BD + p] = val;
      } else {                                         // rare overflow
        int cell = b * NSL + slice;
        int gp = atomicAdd(&bcnt[cell * 16], 1);
        if (gp < BCAPS) raw[(size_t)cell * BCAPS + gp] = val;
      }
    }
    __syncthreads();
    for (int b = t; b < NBUK; b += 256) {
      int c = scnt[b]; if (c > BD) c = BD;
      if (c > 0) {
        int cell = b * NSL + slice;
        int gp = atomicAdd(&bcnt[cell * 16], c);
        for (int k = 0; k < c; ++k) {
          int idx = gp + k;
          if (idx < BCAPS) raw[(size_t)cell * BCAPS + idx] = sbin[b * BD + k];
        }
      }
    }
  } else {
    // ---- el/er path ----
    const int lane = t & 63;
    // Phase A: lane l computes Wfold rows 4l..4l+3 into registers.
    // wfl[c][h] = sum_n W[4l+c][n] * Wl[h][n]   (W row-major [256][64])
    float wfl[4][4] = {{0,0,0,0},{0,0,0,0},{0,0,0,0},{0,0,0,0}};
    float wfr[4][4] = {{0,0,0,0},{0,0,0,0},{0,0,0,0},{0,0,0,0}};
    for (int n = 0; n < 64; ++n) {
      float wlv[4], wrv[4];
      #pragma unroll
      for (int h = 0; h < 4; ++h) { wlv[h] = Wl[h * 64 + n]; wrv[h] = Wr[h * 64 + n]; }
      #pragma unroll
      for (int c = 0; c < 4; ++c) {
        float wv = Wmat[(lane * 4 + c) * 64 + n];   // L2-hot 64KB
        #pragma unroll
        for (int h = 0; h < 4; ++h) {
          wfl[c][h] = fmaf(wv, wlv[h], wfl[c][h]);
          wfr[c][h] = fmaf(wv, wrv[h], wfr[c][h]);
        }
      }
    }
    // Phase B: wave per node, grid-stride. Lane l covers k = 4l..4l+3.
    const int gw = ((blockIdx.x - PARTB) * 256 + t) >> 6;
    const int nw = ELERB * 4;
    for (int node = gw; node < N_NODES; node += nw) {
      f32x4 hv = *(const f32x4*)(hmat + (size_t)node * 256 + lane * 4);
      float al[4] = {0, 0, 0, 0}, ar[4] = {0, 0, 0, 0};
      #pragma unroll
      for (int c = 0; c < 4; ++c)
        #pragma unroll
        for (int h = 0; h < 4; ++h) {
          al[h] = fmaf(hv[c], wfl[c][h], al[h]);
          ar[h] = fmaf(hv[c], wfr[c][h], ar[h]);
        }
      #pragma unroll
      for (int off = 32; off > 0; off >>= 1)
        #pragma unroll
        for (int h = 0; h < 4; ++h) {
          al[h] += __shfl_xor(al[h], off, 64);
          ar[h] += __shfl_xor(ar[h], off, 64);
        }
      if (lane == 0) {
        f32x4 pv = {al[0], al[1], al[2], al[3]};
        f32x4 qv = {ar[0], ar[1], ar[2], ar[3]};
        ((f32x4*)el)[node] = pv;
        ((f32x4*)er)[node] = qv;
      }
    }
  }
}

// ---------------- Kernel 2: bucket CSR+weights  ||  GEMM x16 ----------------
// Blocks [0,2000): per-bucket-half CSR + SoA weights (verbatim round-13 win;
// b = blk>>1, H = blk&1). Blocks [2000,2782): bf16-MFMA GEMM producing ONLY
// x16 (el/er epilogue gone -- now produced in k1; the 128-shfl butterfly is
// deleted from the GEMM). The two paths are data-independent: bucket consumes
// raw/el/er (ready after k1), GEMM produces x16 (consumed only by k_agg) ->
// ~50us bucket hides alongside ~40us GEMM instead of serializing.
__global__ __launch_bounds__(256) void k_bgemm(const float* __restrict__ hmat,
    const float* __restrict__ Wmat,
    const unsigned int* __restrict__ raw, const int* __restrict__ bcnt,
    const float* __restrict__ el, const float* __restrict__ er,
    __half* __restrict__ x16,
    int* __restrict__ dlist, uint2* __restrict__ wts,
    int* __restrict__ rs_s, int* __restrict__ rs_e) {
  __shared__ __align__(16) char smem[36864];
  const int t = threadIdx.x;
  if (blockIdx.x >= BUKB) {
    // ---- GEMM path (x16 only) ----
    unsigned short* Wt = (unsigned short*)smem;   // Wt[n][k], row stride 264
    for (int idx = t; idx < 64 * 256; idx += 256) {
      int k = idx >> 6, n = idx & 63;
      Wt[n * 264 + k] = f2bf(Wmat[idx]);
    }
    __syncthreads();
    const int wave = t >> 6, lane = t & 63;
    const int quad = lane >> 4, l16 = lane & 15;
    const int m0 = (blockIdx.x - BUKB) * 64 + wave * 16;
    int arow = m0 + l16; if (arow >= N_NODES) arow = N_NODES - 1;
    f32x4 c[4] = {{0,0,0,0},{0,0,0,0},{0,0,0,0},{0,0,0,0}};
    const float* aptr = hmat + (size_t)arow * 256 + quad * 8;
    #pragma unroll
    for (int kb = 0; kb < 8; ++kb) {
      f32x4 a0 = *(const f32x4*)(aptr + kb * 32);
      f32x4 a1 = *(const f32x4*)(aptr + kb * 32 + 4);
      short8 a;
      a[0] = (short)f2bf(a0[0]); a[1] = (short)f2bf(a0[1]);
      a[2] = (short)f2bf(a0[2]); a[3] = (short)f2bf(a0[3]);
      a[4] = (short)f2bf(a1[0]); a[5] = (short)f2bf(a1[1]);
      a[6] = (short)f2bf(a1[2]); a[7] = (short)f2bf(a1[3]);
      #pragma unroll
      for (int nt = 0; nt < 4; ++nt) {
        int n = nt * 16 + l16;
        short8 b = *(const short8*)(&Wt[n * 264 + kb * 32 + quad * 8]);
        c[nt] = __builtin_amdgcn_mfma_f32_16x16x32_bf16(a, b, c[nt], 0, 0, 0);
      }
    }
    #pragma unroll
    for (int nt = 0; nt < 4; ++nt) {
      #pragma unroll
      for (int r = 0; r < 4; ++r) {
        int grow = m0 + quad * 4 + r;
        if (grow < N_NODES) x16[grow * 64 + nt * 16 + l16] = __float2half(c[nt][r]);
      }
    }
  } else {
    // ---- bucket path (verbatim round-13) ----
    unsigned int* sraw = (unsigned int*)smem;          // [BCAPH] 5KB
    int* pref = (int*)(smem + BCAPH * 4);              // [NPB+1]
    int* cur  = (int*)(smem + BCAPH * 4 + (NPB + 1) * 4);
    const int b = blockIdx.x >> 1, H = blockIdx.x & 1;
    const int s0 = H * 4;
    int c0 = bcnt[(b * NSL + s0 + 0) * 16]; if (c0 > BCAPS) c0 = BCAPS;
    int c1 = bcnt[(b * NSL + s0 + 1) * 16]; if (c1 > BCAPS) c1 = BCAPS;
    int c2 = bcnt[(b * NSL + s0 + 2) * 16]; if (c2 > BCAPS) c2 = BCAPS;
    int c3 = bcnt[(b * NSL + s0 + 3) * 16]; if (c3 > BCAPS) c3 = BCAPS;
    const int o1 = c0, o2 = c0 + c1, o3 = c0 + c1 + c2, cnt = o3 + c3;
    if (t <= NPB) pref[t] = 0;
    __syncthreads();
    for (int j = t; j < c0; j += 256) { unsigned int r = raw[(size_t)(b*NSL+s0+0)*BCAPS + j]; sraw[j]      = r; atomicAdd(&pref[(int)(r & 255u) + 1], 1); }
    for (int j = t; j < c1; j += 256) { unsigned int r = raw[(size_t)(b*NSL+s0+1)*BCAPS + j]; sraw[o1 + j] = r; atomicAdd(&pref[(int)(r & 255u) + 1], 1); }
    for (int j = t; j < c2; j += 256) { unsigned int r = raw[(size_t)(b*NSL+s0+2)*BCAPS + j]; sraw[o2 + j] = r; atomicAdd(&pref[(int)(r & 255u) + 1], 1); }
    for (int j = t; j < c3; j += 256) { unsigned int r = raw[(size_t)(b*NSL+s0+3)*BCAPS + j]; sraw[o3 + j] = r; atomicAdd(&pref[(int)(r & 255u) + 1], 1); }
    __syncthreads();
    if (t == 0) {
      int run = 0;
      #pragma unroll
      for (int n = 0; n <= NPB; ++n) { run += pref[n]; pref[n] = run; }
    }
    __syncthreads();
    const int wbase = (b * 2 + H) * BCAPH;   // this half's window in dlist/wts
    if (t < NPB) {
      cur[t] = pref[t];
      rs_s[H * N_NODES + b * NPB + t] = wbase + pref[t];
      rs_e[H * N_NODES + b * NPB + t] = wbase + pref[t + 1];
    }
    __syncthreads();
    const int base = b * NPB;
    for (int j = t; j < cnt; j += 256) {
      unsigned int r = sraw[j];
      int sl = (int)(r & 255u);
      int d  = (int)(r >> 8);
      int pos = atomicAdd(&cur[sl], 1);
      f32x4 a = ((const f32x4*)el)[base + sl];   // L1-resident (800B/bucket)
      f32x4 e = ((const f32x4*)er)[d];           // L2-resident (800 KB)
      float w[4];
      #pragma unroll
      for (int hh = 0; hh < 4; ++hh) {
        float tt = a[hh] + e[hh];
        tt = (tt >= 0.f) ? tt : 0.2f * tt;
        w[hh] = __expf(tt);
      }
      union { __half2 h; unsigned int i; } u01, u23;
      u01.h = __floats2half2_rn(w[0], w[1]);
      u23.h = __floats2half2_rn(w[2], w[3]);
      dlist[wbase + pos] = d;                          // 4B scatter
      wts[wbase + pos] = make_uint2(u01.i, u23.i);     // 8B scatter
    }
  }
}

// ---------------- Kernel 3: fused normalize + SpMM + ELU --------------------
// Verbatim round-13 (59.5us proven): wave per node, readfirstlane bounds ->
// uniform s_load SoA streams, SGPR row base, saddr gather, unroll-4.
// DO NOT restructure.
__global__ __launch_bounds__(256) void k_agg(const __half* __restrict__ x16,
    const int* __restrict__ rs_s, const int* __restrict__ rs_e,
    const int* __restrict__ dlist, const uint2* __restrict__ wts,
    const float* __restrict__ bvec, float* __restrict__ out) {
  const int node = (blockIdx.x * 256 + threadIdx.x) >> 6;
  const int lane = threadIdx.x & 63;
  if (node >= N_NODES) return;
  float n0 = 0.f, n1 = 0.f, n2 = 0.f, n3 = 0.f;
  float d0 = 0.f, d1 = 0.f, d2 = 0.f, d3 = 0.f;
  #pragma unroll
  for (int hf = 0; hf < 2; ++hf) {
    const int j0 = __builtin_amdgcn_readfirstlane(rs_s[hf * N_NODES + node]);
    const int j1 = __builtin_amdgcn_readfirstlane(rs_e[hf * N_NODES + node]);
    #pragma unroll 4
    for (int j = j0; j < j1; ++j) {
      const int dd = dlist[j];                         // uniform -> s_load
      const uint2 hw = wts[j];                         // uniform -> s_load x2
      union { unsigned int i; __half2 h; } u01, u23;
      u01.i = hw.x; u23.i = hw.y;
      float2 f01 = __half22float2(u01.h);
      float2 f23 = __half22float2(u23.h);
      const __half* rowp = x16 + ((size_t)dd << 6);    // SGPR row base
      float xv = __half2float(rowp[lane]);             // saddr-form gather
      d0 += f01.x; d1 += f01.y; d2 += f23.x; d3 += f23.y;
      n0 = fmaf(f01.x, xv, n0); n1 = fmaf(f01.y, xv, n1);
      n2 = fmaf(f23.x, xv, n2); n3 = fmaf(f23.y, xv, n3);
    }
  }
  float bv = bvec[lane];
  size_t ob = (size_t)node * 256 + lane;
  float o;
  o = n0 / fmaxf(d0, 1e-12f) + bv; o = (o > 0.f) ? o : (__expf(o) - 1.f); out[ob      ] = o;
  o = n1 / fmaxf(d1, 1e-12f) + bv; o = (o > 0.f) ? o : (__expf(o) - 1.f); out[ob +  64] = o;
  o = n2 / fmaxf(d2, 1e-12f) + bv; o = (o > 0.f) ? o : (__expf(o) - 1.f); out[ob + 128] = o;
  o = n3 / fmaxf(d3, 1e-12f) + bv; o = (o > 0.f) ? o : (__expf(o) - 1.f); out[ob + 192] = o;
}

// ---------------- Launch ----------------------------------------------------
extern "C" void kernel_launch(void* const* d_in, const int* in_sizes, int n_in,
                              void* d_out, int out_size, void* d_ws, size_t ws_size,
                              hipStream_t stream) {
  const float* h  = (const float*)d_in[0];
  const float* W  = (const float*)d_in[1];
  const float* Wl = (const float*)d_in[2];
  const float* Wr = (const float*)d_in[3];
  const float* b  = (const float*)d_in[4];
  const int*   ei = (const int*)d_in[5];
  float* out = (float*)d_out;   // reference output dtype is float32

  char* ws = (char*)d_ws;
  float*        el    = (float*)       (ws + 0);          //    800,000
  float*        er    = (float*)       (ws + 800000);     //    800,000
  int*          bcnt  = (int*)         (ws + 1600000);    //    512,000
  unsigned int* raw   = (unsigned int*)(ws + 2112000);    // 10,240,000
  int*          dlist = (int*)         (ws + 12352000);   // 10,240,000
  uint2*        wts   = (uint2*)       (ws + 22592000);   // 20,480,000
  int*          rs_s  = (int*)         (ws + 43072000);   //    400,000
  int*          rs_e  = (int*)         (ws + 43472000);   //    400,000
  __half*       x16   = (__half*)      (ws + 43872000);   //  6,400,000  (end ~50.3 MB)
  (void)ws_size; (void)in_sizes; (void)n_in; (void)out_size;

  hipMemsetAsync(bcnt, 0, 512000, stream);

  k_peler <<<PARTB + ELERB, 256, 0, stream>>>(h, W, Wl, Wr, ei, bcnt, raw, el, er);
  k_bgemm <<<BUKB + GEMMB,  256, 0, stream>>>(h, W, raw, bcnt, el, er, x16, dlist, wts, rs_s, rs_e);
  k_agg   <<<12500,         256, 0, stream>>>(x16, rs_s, rs_e, dlist, wts, b, out);
}